// Round 5
// baseline (290.450 us; speedup 1.0000x reference)
//
#include <hip/hip_runtime.h>
#include <hip/hip_bf16.h>
#include <stdint.h>

typedef __bf16 bf16x8_t __attribute__((ext_vector_type(8)));
typedef float f32x4 __attribute__((ext_vector_type(4)));

__device__ __forceinline__ unsigned short f2bf_rne(float f) {
  unsigned int u = __float_as_uint(f);
  u += 0x7FFFu + ((u >> 16) & 1u);
  return (unsigned short)(u >> 16);
}

// ---------- kernel 1: alpha[o] = mean|W[o,:]|, wb[o,:] = sign(W[o,:]) as bf16 bits
__global__ __launch_bounds__(256) void k_prep_w(const float* __restrict__ W,
                                                unsigned short* __restrict__ wb,
                                                float* __restrict__ alpha, int K) {
  const int o = blockIdx.x;
  const float* row = W + (size_t)o * K;
  unsigned short* orow = wb + (size_t)o * K;
  const int tid = threadIdx.x;
  float s = 0.f;
  const int nj = K / 1024;
  for (int j = 0; j < nj; ++j) {
    int base = j * 1024 + tid * 4;
    float4 v = *reinterpret_cast<const float4*>(row + base);
    s += fabsf(v.x) + fabsf(v.y) + fabsf(v.z) + fabsf(v.w);
    ushort4 sg;
    sg.x = v.x > 0.f ? 0x3F80u : (v.x < 0.f ? 0xBF80u : 0u);
    sg.y = v.y > 0.f ? 0x3F80u : (v.y < 0.f ? 0xBF80u : 0u);
    sg.z = v.z > 0.f ? 0x3F80u : (v.z < 0.f ? 0xBF80u : 0u);
    sg.w = v.w > 0.f ? 0x3F80u : (v.w < 0.f ? 0xBF80u : 0u);
    *reinterpret_cast<ushort4*>(orow + base) = sg;
  }
  for (int off = 32; off > 0; off >>= 1) s += __shfl_down(s, off);
  __shared__ float red[4];
  int lane = tid & 63, wid = tid >> 6;
  if (lane == 0) red[wid] = s;
  __syncthreads();
  if (tid == 0) alpha[o] = (red[0] + red[1] + red[2] + red[3]) / (float)K;
}

// ---------- kernel 2: x fp32 -> bf16 (RNE)
__global__ __launch_bounds__(256) void k_conv_x(const float* __restrict__ x,
                                                unsigned short* __restrict__ xb,
                                                long long n4) {
  long long i = (long long)blockIdx.x * blockDim.x + threadIdx.x;
  const long long stride = (long long)gridDim.x * blockDim.x;
  for (; i < n4; i += stride) {
    float4 v = reinterpret_cast<const float4*>(x)[i];
    ushort4 o;
    o.x = f2bf_rne(v.x);
    o.y = f2bf_rne(v.y);
    o.z = f2bf_rne(v.z);
    o.w = f2bf_rne(v.w);
    reinterpret_cast<ushort4*>(xb)[i] = o;
  }
}

#define GLDS(gp, lp)                                                                   \
  __builtin_amdgcn_global_load_lds((const __attribute__((address_space(1))) void*)(gp),\
                                   (__attribute__((address_space(3))) void*)(lp), 16, 0, 0)

// ---------- kernel 3b: 256x256 8-phase / 2-K-tile unrolled, BK=64, 512 thr.
// All stage addressing hoisted to 8 stream pointers (+128 elems/iter); LDS
// dests loop-invariant. One half-tile staged per phase; vmcnt(6) at p4/p8.
// C[M,N] = (A[M,K]bf16 . B[N,K]^T) * alpha[n] + bias[n]
__global__ __launch_bounds__(512, 2) void k_gemm256(
    const unsigned short* __restrict__ A, const unsigned short* __restrict__ B,
    const float* __restrict__ alpha, const float* __restrict__ bias,
    float* __restrict__ C, int M, int N, int K, int tm, int tn) {
  // [buf(2)][A/B][256 rows][64 cols] bf16 = 128 KiB
  __shared__ __attribute__((aligned(128))) unsigned short lds[65536];

  const int nwg = tm * tn;
  int bid = blockIdx.x;
  if ((nwg & 7) == 0) bid = (bid & 7) * (nwg >> 3) + (bid >> 3);  // XCD chunked swizzle
  const int mT = bid % tm;  // m-major: consecutive blocks share B-panel (L2)
  const int nT = bid / tm;
  const long m0 = (long)mT * 256;
  const int n0 = nT * 256;

  const int tid = threadIdx.x;
  const int lane = tid & 63;
  const int w = tid >> 6;
  const int wr = w >> 2;
  const int wc = w & 3;
  const int lr = lane & 15;
  const int l16 = lane >> 4;

  // staging: 8 waves x 64 lanes x 16B = 64 rows of 128B per GLDS.
  // LDS dest linear; global source pre-swizzled: LDS(r,s) = global(r, s^(r&7)).
  const int srow = (w << 3) + (lane >> 3);
  const int sslot = (lane & 7) ^ (lane >> 3);
  const unsigned short* gA = A + (size_t)(m0 + srow) * K + sslot * 8;
  const unsigned short* gB = B + (size_t)(n0 + srow) * K + sslot * 8;
  const int sbase = (w << 9);
  const size_t K64 = (size_t)64 * K;   // +64 rows (second GLDS of a stage)
  const size_t H1 = (size_t)128 * K;   // +128 rows (h1 half)

  // per-phase-slot stream pointers, advanced +128 elems (2 tiles) per iteration
  const unsigned short* sAo1 = gA + H1 + 64;   // p1: A odd  h1 (tile 2I+1)
  const unsigned short* sAe0 = gA + 128;       // p2: A even h0 (tile 2I+2)
  const unsigned short* sBe0 = gB + 128;       // p3: B even h0
  const unsigned short* sBe1 = gB + H1 + 128;  // p4: B even h1
  const unsigned short* sAe1 = gA + H1 + 128;  // p5: A even h1
  const unsigned short* sAo0 = gA + 192;       // p6: A odd  h0 (tile 2I+3)
  const unsigned short* sBo0 = gB + 192;       // p7: B odd  h0
  const unsigned short* sBo1 = gB + H1 + 192;  // p8: B odd  h1

  // loop-invariant LDS destinations
  unsigned short* const dAe0 = lds + sbase;                          // buf0 A h0
  unsigned short* const dAe1 = lds + 8192 + sbase;                   // buf0 A h1
  unsigned short* const dBe0 = lds + 16384 + sbase;                  // buf0 B h0
  unsigned short* const dBe1 = lds + 16384 + 8192 + sbase;           // buf0 B h1
  unsigned short* const dAo0 = lds + 32768 + sbase;                  // buf1 A h0
  unsigned short* const dAo1 = lds + 32768 + 8192 + sbase;           // buf1 A h1
  unsigned short* const dBo0 = lds + 32768 + 16384 + sbase;          // buf1 B h0
  unsigned short* const dBo1 = lds + 32768 + 16384 + 8192 + sbase;   // buf1 B h1

#define STG(sp, dp)                \
  do {                             \
    GLDS((sp), (dp));              \
    GLDS((sp) + K64, (dp) + 4096); \
  } while (0)
#define FRAG(off) (*reinterpret_cast<const bf16x8_t*>(&lds[off]))
#define BAR __builtin_amdgcn_s_barrier()
#define LGKM0 asm volatile("s_waitcnt lgkmcnt(0)")

  // per-lane frag base offsets (constant part folds into ds offset: immediates)
  const int sx = lr & 7;
  const int pA0 = (wr * 16 + lr) * 64 + ((0 + l16) ^ sx) * 8;          // kk=0
  const int pA1 = (wr * 16 + lr) * 64 + ((4 + l16) ^ sx) * 8;          // kk=1
  const int pB0 = 16384 + (wc * 16 + lr) * 64 + ((0 + l16) ^ sx) * 8;  // kk=0
  const int pB1 = 16384 + (wc * 16 + lr) * 64 + ((4 + l16) ^ sx) * 8;  // kk=1

  f32x4 acc[8][4];
#pragma unroll
  for (int i = 0; i < 8; ++i)
#pragma unroll
    for (int j = 0; j < 4; ++j) acc[i][j] = (f32x4){0.f, 0.f, 0.f, 0.f};
  bf16x8_t aL[4][2], aH[4][2], bL[2][2], bH[2][2];

  const int NT = K >> 6;       // K-tiles (even, >= 2)
  const int NIT = NT >> 1;     // 8-phase iterations

  auto rdAL = [&](int BUF) {
#pragma unroll
    for (int i = 0; i < 4; ++i) {
      aL[i][0] = FRAG(BUF + pA0 + i * 2048);
      aL[i][1] = FRAG(BUF + pA1 + i * 2048);
    }
  };
  auto rdAH = [&](int BUF) {
#pragma unroll
    for (int i = 0; i < 4; ++i) {
      aH[i][0] = FRAG(BUF + pA0 + (i + 4) * 2048);
      aH[i][1] = FRAG(BUF + pA1 + (i + 4) * 2048);
    }
  };
  auto rdBL = [&](int BUF) {
#pragma unroll
    for (int j = 0; j < 2; ++j) {
      bL[j][0] = FRAG(BUF + pB0 + j * 4096);
      bL[j][1] = FRAG(BUF + pB1 + j * 4096);
    }
  };
  auto rdBH = [&](int BUF) {
#pragma unroll
    for (int j = 0; j < 2; ++j) {
      bH[j][0] = FRAG(BUF + pB0 + (j + 2) * 4096);
      bH[j][1] = FRAG(BUF + pB1 + (j + 2) * 4096);
    }
  };
  auto Q1 = [&]() {  // acc[0..3][0..1] += aL x bL
    __builtin_amdgcn_s_setprio(1);
#pragma unroll
    for (int i = 0; i < 4; ++i)
#pragma unroll
      for (int j = 0; j < 2; ++j) {
        acc[i][j] = __builtin_amdgcn_mfma_f32_16x16x32_bf16(aL[i][0], bL[j][0], acc[i][j], 0, 0, 0);
        acc[i][j] = __builtin_amdgcn_mfma_f32_16x16x32_bf16(aL[i][1], bL[j][1], acc[i][j], 0, 0, 0);
      }
    __builtin_amdgcn_s_setprio(0);
  };
  auto Q2 = [&]() {  // acc[0..3][2..3] += aL x bH
    __builtin_amdgcn_s_setprio(1);
#pragma unroll
    for (int i = 0; i < 4; ++i)
#pragma unroll
      for (int j = 0; j < 2; ++j) {
        acc[i][j + 2] = __builtin_amdgcn_mfma_f32_16x16x32_bf16(aL[i][0], bH[j][0], acc[i][j + 2], 0, 0, 0);
        acc[i][j + 2] = __builtin_amdgcn_mfma_f32_16x16x32_bf16(aL[i][1], bH[j][1], acc[i][j + 2], 0, 0, 0);
      }
    __builtin_amdgcn_s_setprio(0);
  };
  auto Q3 = [&]() {  // acc[4..7][0..1] += aH x bL
    __builtin_amdgcn_s_setprio(1);
#pragma unroll
    for (int i = 0; i < 4; ++i)
#pragma unroll
      for (int j = 0; j < 2; ++j) {
        acc[i + 4][j] = __builtin_amdgcn_mfma_f32_16x16x32_bf16(aH[i][0], bL[j][0], acc[i + 4][j], 0, 0, 0);
        acc[i + 4][j] = __builtin_amdgcn_mfma_f32_16x16x32_bf16(aH[i][1], bL[j][1], acc[i + 4][j], 0, 0, 0);
      }
    __builtin_amdgcn_s_setprio(0);
  };
  auto Q4 = [&]() {  // acc[4..7][2..3] += aH x bH
    __builtin_amdgcn_s_setprio(1);
#pragma unroll
    for (int i = 0; i < 4; ++i)
#pragma unroll
      for (int j = 0; j < 2; ++j) {
        acc[i + 4][j + 2] = __builtin_amdgcn_mfma_f32_16x16x32_bf16(aH[i][0], bH[j][0], acc[i + 4][j + 2], 0, 0, 0);
        acc[i + 4][j + 2] = __builtin_amdgcn_mfma_f32_16x16x32_bf16(aH[i][1], bH[j][1], acc[i + 4][j + 2], 0, 0, 0);
      }
    __builtin_amdgcn_s_setprio(0);
  };

  // ---- prologue: T0 full (8 GLDS) + T1.A0/B0/B1 (6 GLDS); drain T0, keep 6 in flight
  STG(gA, dAe0);
  STG(gB, dBe0);
  STG(gB + H1, dBe1);
  STG(gA + H1, dAe1);
  STG(gA + 64, dAo0);
  STG(gB + 64, dBo0);
  STG(gB + H1 + 64, dBo1);
  asm volatile("s_waitcnt vmcnt(6)" ::: "memory");
  BAR;

  for (int I = 0; I < NIT; ++I) {
    const bool LAST = (I == NIT - 1);
    // p1: even tile, quadrant (Alo,Blo); stage odd.A1
    rdAL(0); rdBL(0);
    STG(sAo1, dAo1);
    BAR; LGKM0; Q1(); BAR;
    // p2: quadrant (Alo,Bhi); stage even+2.A0
    rdBH(0);
    if (!LAST) STG(sAe0, dAe0);
    BAR; LGKM0; Q2(); BAR;
    // p3: quadrant (Ahi,Blo); stage even+2.B0
    rdAH(0);
    if (!LAST) STG(sBe0, dBe0);
    BAR; LGKM0; Q3(); BAR;
    // p4: quadrant (Ahi,Bhi); stage even+2.B1; counted vmcnt -> odd tile landed
    if (!LAST) {
      STG(sBe1, dBe1);
      asm volatile("s_waitcnt vmcnt(6)" ::: "memory");
    } else {
      asm volatile("s_waitcnt vmcnt(0)" ::: "memory");
    }
    BAR; Q4(); BAR;
    // p5: odd tile, quadrant (Alo,Blo); stage even+2.A1
    rdAL(32768); rdBL(32768);
    if (!LAST) STG(sAe1, dAe1);
    BAR; LGKM0; Q1(); BAR;
    // p6: quadrant (Alo,Bhi); stage odd+2.A0
    rdBH(32768);
    if (!LAST) STG(sAo0, dAo0);
    BAR; LGKM0; Q2(); BAR;
    // p7: quadrant (Ahi,Blo); stage odd+2.B0
    rdAH(32768);
    if (!LAST) STG(sBo0, dBo0);
    BAR; LGKM0; Q3(); BAR;
    // p8: quadrant (Ahi,Bhi); stage odd+2.B1; counted vmcnt -> even+2 landed
    if (!LAST) {
      STG(sBo1, dBo1);
      asm volatile("s_waitcnt vmcnt(6)" ::: "memory");
    }
    BAR; Q4(); BAR;
    // advance streams by 2 K-tiles
    sAo1 += 128; sAe0 += 128; sBe0 += 128; sBe1 += 128;
    sAe1 += 128; sAo0 += 128; sBo0 += 128; sBo1 += 128;
  }

  // ---- epilogue: C/D frag layout col=lane&15, row=(lane>>4)*4+r [m89]
#pragma unroll
  for (int j = 0; j < 4; ++j) {
    const int col = n0 + j * 64 + wc * 16 + lr;
    const float al = alpha[col];
    const float bi = bias[col];
#pragma unroll
    for (int i = 0; i < 8; ++i) {
      const long row = m0 + i * 32 + wr * 16 + l16 * 4;
      f32x4 v = acc[i][j];
#pragma unroll
      for (int r = 0; r < 4; ++r) C[(size_t)(row + r) * N + col] = v[r] * al + bi;
    }
  }
#undef STG
#undef FRAG
#undef BAR
#undef LGKM0
}

// ---------- kernel 3a: verified 128x128 2-phase fallback (round-0, passed)
__global__ __launch_bounds__(256) void k_gemm(
    const unsigned short* __restrict__ A, const unsigned short* __restrict__ B,
    const float* __restrict__ alpha, const float* __restrict__ bias,
    float* __restrict__ C, int M, int N, int K, int tm) {
  __shared__ unsigned short tA[128 * 32];
  __shared__ unsigned short tB[128 * 32];
  const int bid = blockIdx.x;
  const int mT = bid % tm;
  const int nT = bid / tm;
  const int m0 = mT * 128, n0 = nT * 128;
  const int tid = threadIdx.x;
  const int lane = tid & 63;
  const int wid = tid >> 6;
  const int wr = wid >> 1, wc = wid & 1;
  f32x4 acc[4][4];
#pragma unroll
  for (int i = 0; i < 4; ++i)
#pragma unroll
    for (int j = 0; j < 4; ++j) acc[i][j] = (f32x4){0.f, 0.f, 0.f, 0.f};
  const int srow = wid * 16 + (lane >> 2);
  const int scol = (lane & 3) * 8;
  const unsigned short* gA0 = A + (size_t)(m0 + srow) * K + scol;
  const unsigned short* gA1 = A + (size_t)(m0 + 64 + srow) * K + scol;
  const unsigned short* gB0 = B + (size_t)(n0 + srow) * K + scol;
  const unsigned short* gB1 = B + (size_t)(n0 + 64 + srow) * K + scol;
  unsigned short* lA0 = tA + wid * 512;
  unsigned short* lA1 = tA + 2048 + wid * 512;
  unsigned short* lB0 = tB + wid * 512;
  unsigned short* lB1 = tB + 2048 + wid * 512;
  const int lr = lane & 15;
  const int kb = lane >> 4;
  int aoff[4], boff[4];
#pragma unroll
  for (int i = 0; i < 4; ++i) {
    aoff[i] = (wr * 64 + i * 16 + lr) * 32 + kb * 8;
    boff[i] = (wc * 64 + i * 16 + lr) * 32 + kb * 8;
  }
  for (int k0 = 0; k0 < K; k0 += 32) {
    __syncthreads();
    GLDS(gA0 + k0, lA0);
    GLDS(gA1 + k0, lA1);
    GLDS(gB0 + k0, lB0);
    GLDS(gB1 + k0, lB1);
    __syncthreads();
    bf16x8_t af[4], bfr[4];
#pragma unroll
    for (int i = 0; i < 4; ++i) af[i] = *reinterpret_cast<const bf16x8_t*>(&tA[aoff[i]]);
#pragma unroll
    for (int j = 0; j < 4; ++j) bfr[j] = *reinterpret_cast<const bf16x8_t*>(&tB[boff[j]]);
#pragma unroll
    for (int i = 0; i < 4; ++i)
#pragma unroll
      for (int j = 0; j < 4; ++j)
        acc[i][j] = __builtin_amdgcn_mfma_f32_16x16x32_bf16(af[i], bfr[j], acc[i][j], 0, 0, 0);
  }
#pragma unroll
  for (int j = 0; j < 4; ++j) {
    const int col = n0 + wc * 64 + j * 16 + lr;
    const float al = alpha[col];
    const float bi = bias[col];
#pragma unroll
    for (int i = 0; i < 4; ++i) {
      const int row = m0 + wr * 64 + i * 16 + kb * 4;
      f32x4 v = acc[i][j];
#pragma unroll
      for (int r = 0; r < 4; ++r) C[(size_t)(row + r) * N + col] = v[r] * al + bi;
    }
  }
}

// ---------- fallback: slow but correct, zero scratch
__global__ void k_naive(const float* __restrict__ x, const float* __restrict__ W,
                        const float* __restrict__ bias, float* __restrict__ out,
                        int M, int N, int K) {
  int m = blockIdx.x;
  int n = blockIdx.y * 256 + threadIdx.x;
  if (n >= N) return;
  const float* xr = x + (size_t)m * K;
  const float* wr = W + (size_t)n * K;
  float sa = 0.f, s = 0.f;
  for (int i = 0; i < K; ++i) {
    float wv = wr[i];
    sa += fabsf(wv);
    float sg = (wv > 0.f) ? 1.f : ((wv < 0.f) ? -1.f : 0.f);
    s += xr[i] * sg;
  }
  out[(size_t)m * N + n] = (sa / (float)K) * s + bias[n];
}

extern "C" void kernel_launch(void* const* d_in, const int* in_sizes, int n_in,
                              void* d_out, int out_size, void* d_ws, size_t ws_size,
                              hipStream_t stream) {
  const float* x = (const float*)d_in[0];
  const float* w = (const float*)d_in[1];
  const float* bias = (const float*)d_in[2];
  float* out = (float*)d_out;

  const int D_OUT = in_sizes[2];
  const int D_IN = in_sizes[1] / D_OUT;
  const long long M = (long long)in_sizes[0] / D_IN;
  const int N = D_OUT, K = D_IN;

  const size_t xbB = (size_t)M * K * 2;
  const size_t wbB = (size_t)N * K * 2;
  const size_t need = xbB + wbB + (size_t)N * 4;

  const bool prep_ok = (ws_size >= need) && (K % 1024 == 0) && ((M * K) % 4 == 0);
  const bool f256 = prep_ok && (M % 256 == 0) && (N % 256 == 0) && (K % 128 == 0);
  const bool f128 = prep_ok && (M % 128 == 0) && (N % 128 == 0) && (K % 32 == 0);

  if (f256 || f128) {
    unsigned short* xb = (unsigned short*)d_ws;
    unsigned short* wb = (unsigned short*)((char*)d_ws + xbB);
    float* alpha = (float*)((char*)d_ws + xbB + wbB);
    k_prep_w<<<N, 256, 0, stream>>>(w, wb, alpha, K);
    long long n4 = M * (long long)K / 4;
    k_conv_x<<<2048, 256, 0, stream>>>(x, xb, n4);
    bool done = false;
    if (f256) {
      const int tm = (int)(M / 256), tn = N / 256;
      k_gemm256<<<tm * tn, 512, 0, stream>>>(xb, wb, alpha, bias, out, (int)M, N, K, tm, tn);
      done = (hipGetLastError() == hipSuccess);
    }
    if (!done) {
      const int tm = (int)(M / 128), tn = N / 128;
      k_gemm<<<tm * tn, 256, 0, stream>>>(xb, wb, alpha, bias, out, (int)M, N, K, tm);
    }
  } else {
    dim3 g((unsigned)M, (unsigned)((N + 255) / 256));
    k_naive<<<g, 256, 0, stream>>>(x, w, bias, out, (int)M, N, K);
  }
}

// Round 6
// 271.205 us; speedup vs baseline: 1.0710x; 1.0710x over previous
//
#include <hip/hip_runtime.h>
#include <hip/hip_bf16.h>
#include <stdint.h>

typedef __bf16 bf16x8_t __attribute__((ext_vector_type(8)));
typedef float f32x4 __attribute__((ext_vector_type(4)));

__device__ __forceinline__ unsigned short f2bf_rne(float f) {
  unsigned int u = __float_as_uint(f);
  u += 0x7FFFu + ((u >> 16) & 1u);
  return (unsigned short)(u >> 16);
}

// ---------- kernel 1: alpha[o] = mean|W[o,:]|, wb[o,:] = sign(W[o,:]) as bf16 bits
__global__ __launch_bounds__(256) void k_prep_w(const float* __restrict__ W,
                                                unsigned short* __restrict__ wb,
                                                float* __restrict__ alpha, int K) {
  const int o = blockIdx.x;
  const float* row = W + (size_t)o * K;
  unsigned short* orow = wb + (size_t)o * K;
  const int tid = threadIdx.x;
  float s = 0.f;
  const int nj = K / 1024;
  for (int j = 0; j < nj; ++j) {
    int base = j * 1024 + tid * 4;
    float4 v = *reinterpret_cast<const float4*>(row + base);
    s += fabsf(v.x) + fabsf(v.y) + fabsf(v.z) + fabsf(v.w);
    ushort4 sg;
    sg.x = v.x > 0.f ? 0x3F80u : (v.x < 0.f ? 0xBF80u : 0u);
    sg.y = v.y > 0.f ? 0x3F80u : (v.y < 0.f ? 0xBF80u : 0u);
    sg.z = v.z > 0.f ? 0x3F80u : (v.z < 0.f ? 0xBF80u : 0u);
    sg.w = v.w > 0.f ? 0x3F80u : (v.w < 0.f ? 0xBF80u : 0u);
    *reinterpret_cast<ushort4*>(orow + base) = sg;
  }
  for (int off = 32; off > 0; off >>= 1) s += __shfl_down(s, off);
  __shared__ float red[4];
  int lane = tid & 63, wid = tid >> 6;
  if (lane == 0) red[wid] = s;
  __syncthreads();
  if (tid == 0) alpha[o] = (red[0] + red[1] + red[2] + red[3]) / (float)K;
}

// ---------- kernel 2: x fp32 -> bf16 (RNE)
__global__ __launch_bounds__(256) void k_conv_x(const float* __restrict__ x,
                                                unsigned short* __restrict__ xb,
                                                long long n4) {
  long long i = (long long)blockIdx.x * blockDim.x + threadIdx.x;
  const long long stride = (long long)gridDim.x * blockDim.x;
  for (; i < n4; i += stride) {
    float4 v = reinterpret_cast<const float4*>(x)[i];
    ushort4 o;
    o.x = f2bf_rne(v.x);
    o.y = f2bf_rne(v.y);
    o.z = f2bf_rne(v.z);
    o.w = f2bf_rne(v.w);
    reinterpret_cast<ushort4*>(xb)[i] = o;
  }
}

#define GLDS(gp, lp)                                                                   \
  __builtin_amdgcn_global_load_lds((const __attribute__((address_space(1))) void*)(gp),\
                                   (__attribute__((address_space(3))) void*)(lp), 16, 0, 0)

// ---------- kernel 3b: 256x256 8-phase / 2-K-tile unrolled, BK=64, 512 thr.
// XCD-disjoint A-panel mapping: XCD c covers mT = c*mPC..+mPC, ALL nT ->
// per-XCD A traffic = mPC panels instead of the whole A matrix.
// C[M,N] = (A[M,K]bf16 . B[N,K]^T) * alpha[n] + bias[n]
__global__ __launch_bounds__(512, 2) void k_gemm256(
    const unsigned short* __restrict__ A, const unsigned short* __restrict__ B,
    const float* __restrict__ alpha, const float* __restrict__ bias,
    float* __restrict__ C, int M, int N, int K, int tm, int tn) {
  // [buf(2)][A/B][256 rows][64 cols] bf16 = 128 KiB
  __shared__ __attribute__((aligned(128))) unsigned short lds[65536];

  const int nwg = tm * tn;
  const int chunk = nwg >> 3;
  int mT, nT;
  {
    const int bid = blockIdx.x;
    const int mPC = (tn > 0 && chunk % tn == 0) ? (chunk / tn) : 0;
    if ((nwg & 7) == 0 && mPC > 0 && (tm % mPC) == 0) {
      // physical dispatch round-robins XCDs: XCD = bid&7 gets a contiguous
      // logical chunk = mPC consecutive A-panels x all tn B-panels
      const int c = bid & 7;
      const int q = bid >> 3;
      mT = c * mPC + (q % mPC);
      nT = q / mPC;
    } else {
      mT = bid % tm;
      nT = bid / tm;
    }
  }
  const long m0 = (long)mT * 256;
  const int n0 = nT * 256;

  const int tid = threadIdx.x;
  const int lane = tid & 63;
  const int w = tid >> 6;
  const int wr = w >> 2;
  const int wc = w & 3;
  const int lr = lane & 15;
  const int l16 = lane >> 4;

  // staging: 8 waves x 64 lanes x 16B = 64 rows of 128B per GLDS.
  // LDS dest linear; global source pre-swizzled: LDS(r,s) = global(r, s^(r&7)).
  const int srow = (w << 3) + (lane >> 3);
  const int sslot = (lane & 7) ^ (lane >> 3);
  const unsigned short* gA = A + (size_t)(m0 + srow) * K + sslot * 8;
  const unsigned short* gB = B + (size_t)(n0 + srow) * K + sslot * 8;
  const int sbase = (w << 9);
  const size_t K64 = (size_t)64 * K;   // +64 rows (second GLDS of a stage)
  const size_t H1 = (size_t)128 * K;   // +128 rows (h1 half)

  // per-phase-slot stream pointers, advanced +128 elems (2 tiles) per iteration
  const unsigned short* sAo1 = gA + H1 + 64;   // p1: A odd  h1 (tile 2I+1)
  const unsigned short* sAe0 = gA + 128;       // p2: A even h0 (tile 2I+2)
  const unsigned short* sBe0 = gB + 128;       // p3: B even h0
  const unsigned short* sBe1 = gB + H1 + 128;  // p4: B even h1
  const unsigned short* sAe1 = gA + H1 + 128;  // p5: A even h1
  const unsigned short* sAo0 = gA + 192;       // p6: A odd  h0 (tile 2I+3)
  const unsigned short* sBo0 = gB + 192;       // p7: B odd  h0
  const unsigned short* sBo1 = gB + H1 + 192;  // p8: B odd  h1

  // loop-invariant LDS destinations
  unsigned short* const dAe0 = lds + sbase;                          // buf0 A h0
  unsigned short* const dAe1 = lds + 8192 + sbase;                   // buf0 A h1
  unsigned short* const dBe0 = lds + 16384 + sbase;                  // buf0 B h0
  unsigned short* const dBe1 = lds + 16384 + 8192 + sbase;           // buf0 B h1
  unsigned short* const dAo0 = lds + 32768 + sbase;                  // buf1 A h0
  unsigned short* const dAo1 = lds + 32768 + 8192 + sbase;           // buf1 A h1
  unsigned short* const dBo0 = lds + 32768 + 16384 + sbase;          // buf1 B h0
  unsigned short* const dBo1 = lds + 32768 + 16384 + 8192 + sbase;   // buf1 B h1

#define STG(sp, dp)                \
  do {                             \
    GLDS((sp), (dp));              \
    GLDS((sp) + K64, (dp) + 4096); \
  } while (0)
#define FRAG(off) (*reinterpret_cast<const bf16x8_t*>(&lds[off]))
#define BAR __builtin_amdgcn_s_barrier()
#define LGKM0 asm volatile("s_waitcnt lgkmcnt(0)")

  // per-lane frag base offsets (constant part folds into ds offset: immediates)
  const int sx = lr & 7;
  const int pA0 = (wr * 16 + lr) * 64 + ((0 + l16) ^ sx) * 8;          // kk=0
  const int pA1 = (wr * 16 + lr) * 64 + ((4 + l16) ^ sx) * 8;          // kk=1
  const int pB0 = 16384 + (wc * 16 + lr) * 64 + ((0 + l16) ^ sx) * 8;  // kk=0
  const int pB1 = 16384 + (wc * 16 + lr) * 64 + ((4 + l16) ^ sx) * 8;  // kk=1

  f32x4 acc[8][4];
#pragma unroll
  for (int i = 0; i < 8; ++i)
#pragma unroll
    for (int j = 0; j < 4; ++j) acc[i][j] = (f32x4){0.f, 0.f, 0.f, 0.f};
  bf16x8_t aL[4][2], aH[4][2], bL[2][2], bH[2][2];

  const int NT = K >> 6;       // K-tiles (even, >= 2)
  const int NIT = NT >> 1;     // 8-phase iterations

  auto rdAL = [&](int BUF) {
#pragma unroll
    for (int i = 0; i < 4; ++i) {
      aL[i][0] = FRAG(BUF + pA0 + i * 2048);
      aL[i][1] = FRAG(BUF + pA1 + i * 2048);
    }
  };
  auto rdAH = [&](int BUF) {
#pragma unroll
    for (int i = 0; i < 4; ++i) {
      aH[i][0] = FRAG(BUF + pA0 + (i + 4) * 2048);
      aH[i][1] = FRAG(BUF + pA1 + (i + 4) * 2048);
    }
  };
  auto rdBL = [&](int BUF) {
#pragma unroll
    for (int j = 0; j < 2; ++j) {
      bL[j][0] = FRAG(BUF + pB0 + j * 4096);
      bL[j][1] = FRAG(BUF + pB1 + j * 4096);
    }
  };
  auto rdBH = [&](int BUF) {
#pragma unroll
    for (int j = 0; j < 2; ++j) {
      bH[j][0] = FRAG(BUF + pB0 + (j + 2) * 4096);
      bH[j][1] = FRAG(BUF + pB1 + (j + 2) * 4096);
    }
  };
  auto Q1 = [&]() {  // acc[0..3][0..1] += aL x bL
    __builtin_amdgcn_s_setprio(1);
#pragma unroll
    for (int i = 0; i < 4; ++i)
#pragma unroll
      for (int j = 0; j < 2; ++j) {
        acc[i][j] = __builtin_amdgcn_mfma_f32_16x16x32_bf16(aL[i][0], bL[j][0], acc[i][j], 0, 0, 0);
        acc[i][j] = __builtin_amdgcn_mfma_f32_16x16x32_bf16(aL[i][1], bL[j][1], acc[i][j], 0, 0, 0);
      }
    __builtin_amdgcn_s_setprio(0);
  };
  auto Q2 = [&]() {  // acc[0..3][2..3] += aL x bH
    __builtin_amdgcn_s_setprio(1);
#pragma unroll
    for (int i = 0; i < 4; ++i)
#pragma unroll
      for (int j = 0; j < 2; ++j) {
        acc[i][j + 2] = __builtin_amdgcn_mfma_f32_16x16x32_bf16(aL[i][0], bH[j][0], acc[i][j + 2], 0, 0, 0);
        acc[i][j + 2] = __builtin_amdgcn_mfma_f32_16x16x32_bf16(aL[i][1], bH[j][1], acc[i][j + 2], 0, 0, 0);
      }
    __builtin_amdgcn_s_setprio(0);
  };
  auto Q3 = [&]() {  // acc[4..7][0..1] += aH x bL
    __builtin_amdgcn_s_setprio(1);
#pragma unroll
    for (int i = 0; i < 4; ++i)
#pragma unroll
      for (int j = 0; j < 2; ++j) {
        acc[i + 4][j] = __builtin_amdgcn_mfma_f32_16x16x32_bf16(aH[i][0], bL[j][0], acc[i + 4][j], 0, 0, 0);
        acc[i + 4][j] = __builtin_amdgcn_mfma_f32_16x16x32_bf16(aH[i][1], bL[j][1], acc[i + 4][j], 0, 0, 0);
      }
    __builtin_amdgcn_s_setprio(0);
  };
  auto Q4 = [&]() {  // acc[4..7][2..3] += aH x bH
    __builtin_amdgcn_s_setprio(1);
#pragma unroll
    for (int i = 0; i < 4; ++i)
#pragma unroll
      for (int j = 0; j < 2; ++j) {
        acc[i + 4][j + 2] = __builtin_amdgcn_mfma_f32_16x16x32_bf16(aH[i][0], bH[j][0], acc[i + 4][j + 2], 0, 0, 0);
        acc[i + 4][j + 2] = __builtin_amdgcn_mfma_f32_16x16x32_bf16(aH[i][1], bH[j][1], acc[i + 4][j + 2], 0, 0, 0);
      }
    __builtin_amdgcn_s_setprio(0);
  };

  // ---- prologue: T0 full (8 GLDS) + T1.A0/B0/B1 (6 GLDS); drain T0, keep 6 in flight
  STG(gA, dAe0);
  STG(gB, dBe0);
  STG(gB + H1, dBe1);
  STG(gA + H1, dAe1);
  STG(gA + 64, dAo0);
  STG(gB + 64, dBo0);
  STG(gB + H1 + 64, dBo1);
  asm volatile("s_waitcnt vmcnt(6)" ::: "memory");
  BAR;

  for (int I = 0; I < NIT; ++I) {
    const bool LAST = (I == NIT - 1);
    // p1: even tile, quadrant (Alo,Blo); stage odd.A1
    rdAL(0); rdBL(0);
    STG(sAo1, dAo1);
    BAR; LGKM0; Q1(); BAR;
    // p2: quadrant (Alo,Bhi); stage even+2.A0
    rdBH(0);
    if (!LAST) STG(sAe0, dAe0);
    BAR; LGKM0; Q2(); BAR;
    // p3: quadrant (Ahi,Blo); stage even+2.B0
    rdAH(0);
    if (!LAST) STG(sBe0, dBe0);
    BAR; LGKM0; Q3(); BAR;
    // p4: quadrant (Ahi,Bhi); stage even+2.B1; counted vmcnt -> odd tile landed
    if (!LAST) {
      STG(sBe1, dBe1);
      asm volatile("s_waitcnt vmcnt(6)" ::: "memory");
    } else {
      asm volatile("s_waitcnt vmcnt(0)" ::: "memory");
    }
    BAR; Q4(); BAR;
    // p5: odd tile, quadrant (Alo,Blo); stage even+2.A1
    rdAL(32768); rdBL(32768);
    if (!LAST) STG(sAe1, dAe1);
    BAR; LGKM0; Q1(); BAR;
    // p6: quadrant (Alo,Bhi); stage odd+2.A0
    rdBH(32768);
    if (!LAST) STG(sAo0, dAo0);
    BAR; LGKM0; Q2(); BAR;
    // p7: quadrant (Ahi,Blo); stage odd+2.B0
    rdAH(32768);
    if (!LAST) STG(sBo0, dBo0);
    BAR; LGKM0; Q3(); BAR;
    // p8: quadrant (Ahi,Bhi); stage odd+2.B1; counted vmcnt -> even+2 landed
    if (!LAST) {
      STG(sBo1, dBo1);
      asm volatile("s_waitcnt vmcnt(6)" ::: "memory");
    }
    BAR; Q4(); BAR;
    // advance streams by 2 K-tiles
    sAo1 += 128; sAe0 += 128; sBe0 += 128; sBe1 += 128;
    sAe1 += 128; sAo0 += 128; sBo0 += 128; sBo1 += 128;
  }

  // ---- epilogue: C/D frag layout col=lane&15, row=(lane>>4)*4+r [m89]
#pragma unroll
  for (int j = 0; j < 4; ++j) {
    const int col = n0 + j * 64 + wc * 16 + lr;
    const float al = alpha[col];
    const float bi = bias[col];
#pragma unroll
    for (int i = 0; i < 8; ++i) {
      const long row = m0 + i * 32 + wr * 16 + l16 * 4;
      f32x4 v = acc[i][j];
#pragma unroll
      for (int r = 0; r < 4; ++r) C[(size_t)(row + r) * N + col] = v[r] * al + bi;
    }
  }
#undef STG
#undef FRAG
#undef BAR
#undef LGKM0
}

// ---------- kernel 3a: verified 128x128 2-phase fallback (round-0, passed)
__global__ __launch_bounds__(256) void k_gemm(
    const unsigned short* __restrict__ A, const unsigned short* __restrict__ B,
    const float* __restrict__ alpha, const float* __restrict__ bias,
    float* __restrict__ C, int M, int N, int K, int tm) {
  __shared__ unsigned short tA[128 * 32];
  __shared__ unsigned short tB[128 * 32];
  const int bid = blockIdx.x;
  const int mT = bid % tm;
  const int nT = bid / tm;
  const int m0 = mT * 128, n0 = nT * 128;
  const int tid = threadIdx.x;
  const int lane = tid & 63;
  const int wid = tid >> 6;
  const int wr = wid >> 1, wc = wid & 1;
  f32x4 acc[4][4];
#pragma unroll
  for (int i = 0; i < 4; ++i)
#pragma unroll
    for (int j = 0; j < 4; ++j) acc[i][j] = (f32x4){0.f, 0.f, 0.f, 0.f};
  const int srow = wid * 16 + (lane >> 2);
  const int scol = (lane & 3) * 8;
  const unsigned short* gA0 = A + (size_t)(m0 + srow) * K + scol;
  const unsigned short* gA1 = A + (size_t)(m0 + 64 + srow) * K + scol;
  const unsigned short* gB0 = B + (size_t)(n0 + srow) * K + scol;
  const unsigned short* gB1 = B + (size_t)(n0 + 64 + srow) * K + scol;
  unsigned short* lA0 = tA + wid * 512;
  unsigned short* lA1 = tA + 2048 + wid * 512;
  unsigned short* lB0 = tB + wid * 512;
  unsigned short* lB1 = tB + 2048 + wid * 512;
  const int lr = lane & 15;
  const int kb = lane >> 4;
  int aoff[4], boff[4];
#pragma unroll
  for (int i = 0; i < 4; ++i) {
    aoff[i] = (wr * 64 + i * 16 + lr) * 32 + kb * 8;
    boff[i] = (wc * 64 + i * 16 + lr) * 32 + kb * 8;
  }
  for (int k0 = 0; k0 < K; k0 += 32) {
    __syncthreads();
    GLDS(gA0 + k0, lA0);
    GLDS(gA1 + k0, lA1);
    GLDS(gB0 + k0, lB0);
    GLDS(gB1 + k0, lB1);
    __syncthreads();
    bf16x8_t af[4], bfr[4];
#pragma unroll
    for (int i = 0; i < 4; ++i) af[i] = *reinterpret_cast<const bf16x8_t*>(&tA[aoff[i]]);
#pragma unroll
    for (int j = 0; j < 4; ++j) bfr[j] = *reinterpret_cast<const bf16x8_t*>(&tB[boff[j]]);
#pragma unroll
    for (int i = 0; i < 4; ++i)
#pragma unroll
      for (int j = 0; j < 4; ++j)
        acc[i][j] = __builtin_amdgcn_mfma_f32_16x16x32_bf16(af[i], bfr[j], acc[i][j], 0, 0, 0);
  }
#pragma unroll
  for (int j = 0; j < 4; ++j) {
    const int col = n0 + wc * 64 + j * 16 + lr;
    const float al = alpha[col];
    const float bi = bias[col];
#pragma unroll
    for (int i = 0; i < 4; ++i) {
      const int row = m0 + wr * 64 + i * 16 + kb * 4;
      f32x4 v = acc[i][j];
#pragma unroll
      for (int r = 0; r < 4; ++r) C[(size_t)(row + r) * N + col] = v[r] * al + bi;
    }
  }
}

// ---------- fallback: slow but correct, zero scratch
__global__ void k_naive(const float* __restrict__ x, const float* __restrict__ W,
                        const float* __restrict__ bias, float* __restrict__ out,
                        int M, int N, int K) {
  int m = blockIdx.x;
  int n = blockIdx.y * 256 + threadIdx.x;
  if (n >= N) return;
  const float* xr = x + (size_t)m * K;
  const float* wr = W + (size_t)n * K;
  float sa = 0.f, s = 0.f;
  for (int i = 0; i < K; ++i) {
    float wv = wr[i];
    sa += fabsf(wv);
    float sg = (wv > 0.f) ? 1.f : ((wv < 0.f) ? -1.f : 0.f);
    s += xr[i] * sg;
  }
  out[(size_t)m * N + n] = (sa / (float)K) * s + bias[n];
}

extern "C" void kernel_launch(void* const* d_in, const int* in_sizes, int n_in,
                              void* d_out, int out_size, void* d_ws, size_t ws_size,
                              hipStream_t stream) {
  const float* x = (const float*)d_in[0];
  const float* w = (const float*)d_in[1];
  const float* bias = (const float*)d_in[2];
  float* out = (float*)d_out;

  const int D_OUT = in_sizes[2];
  const int D_IN = in_sizes[1] / D_OUT;
  const long long M = (long long)in_sizes[0] / D_IN;
  const int N = D_OUT, K = D_IN;

  const size_t xbB = (size_t)M * K * 2;
  const size_t wbB = (size_t)N * K * 2;
  const size_t need = xbB + wbB + (size_t)N * 4;

  const bool prep_ok = (ws_size >= need) && (K % 1024 == 0) && ((M * K) % 4 == 0);
  const bool f256 = prep_ok && (M % 256 == 0) && (N % 256 == 0) && (K % 128 == 0);
  const bool f128 = prep_ok && (M % 128 == 0) && (N % 128 == 0) && (K % 32 == 0);

  if (f256 || f128) {
    unsigned short* xb = (unsigned short*)d_ws;
    unsigned short* wb = (unsigned short*)((char*)d_ws + xbB);
    float* alpha = (float*)((char*)d_ws + xbB + wbB);
    k_prep_w<<<N, 256, 0, stream>>>(w, wb, alpha, K);
    long long n4 = M * (long long)K / 4;
    k_conv_x<<<2048, 256, 0, stream>>>(x, xb, n4);
    bool done = false;
    if (f256) {
      const int tm = (int)(M / 256), tn = N / 256;
      k_gemm256<<<tm * tn, 512, 0, stream>>>(xb, wb, alpha, bias, out, (int)M, N, K, tm, tn);
      done = (hipGetLastError() == hipSuccess);
    }
    if (!done) {
      const int tm = (int)(M / 128), tn = N / 128;
      k_gemm<<<tm * tn, 256, 0, stream>>>(xb, wb, alpha, bias, out, (int)M, N, K, tm);
    }
  } else {
    dim3 g((unsigned)M, (unsigned)((N + 255) / 256));
    k_naive<<<g, 256, 0, stream>>>(x, w, bias, out, (int)M, N, K);
  }
}